// Round 2
// 11226.286 us; speedup vs baseline: 2.8490x; 2.8490x over previous
//
#include <hip/hip_runtime.h>
#include <stdint.h>

#define TT     512
#define NH     8
#define DIMIN  768
#define WIDTH  8192
#define NE     128
#define DHQK   16
#define DHV    1024
#define BB     8
#define MROWS  4096   // B*T

// x0 = x - b  (fp32)
__global__ __launch_bounds__(256) void sub_bias(const float* __restrict__ x,
                                                const float* __restrict__ bias,
                                                float* __restrict__ x0, int n) {
  int i = blockIdx.x * 256 + threadIdx.x;
  if (i < n) x0[i] = x[i] - bias[i % DIMIN];
}

// C[m,n] = act( scale * sum_k A[m,k]*B[n,k] + bias[n] )
// A fp32 (lda=K), B fp32 (ldb=K), C fp32 (ldc=N). 64x64 tile, BK=16, 4x4/thread.
// fp32 partials folded into fp64 per K-tile (top-k stability).
__global__ __launch_bounds__(256) void gemm_nt(const float* __restrict__ A,
                                               const float* __restrict__ Bw,
                                               const float* __restrict__ bias,
                                               float* __restrict__ C,
                                               int M, int N, int K,
                                               float scale, int act) {
  __shared__ float As[16][64];
  __shared__ float Bs[16][64];
  const int tid = threadIdx.x;
  const int m0 = blockIdx.y * 64;
  const int n0 = blockIdx.x * 64;
  const int lr = tid >> 2;          // 0..63
  const int lc = (tid & 3) << 2;    // 0,4,8,12
  const int tm = (tid >> 4) << 2;
  const int tn = (tid & 15) << 2;
  double dacc[16];
#pragma unroll
  for (int i = 0; i < 16; i++) dacc[i] = 0.0;

  for (int k0 = 0; k0 < K; k0 += 16) {
    float4 a4 = *(const float4*)(A + (size_t)(m0 + lr) * K + k0 + lc);
    float4 b4 = *(const float4*)(Bw + (size_t)(n0 + lr) * K + k0 + lc);
    As[lc + 0][lr] = a4.x; As[lc + 1][lr] = a4.y;
    As[lc + 2][lr] = a4.z; As[lc + 3][lr] = a4.w;
    Bs[lc + 0][lr] = b4.x; Bs[lc + 1][lr] = b4.y;
    Bs[lc + 2][lr] = b4.z; Bs[lc + 3][lr] = b4.w;
    __syncthreads();
    float facc[16];
#pragma unroll
    for (int i = 0; i < 16; i++) facc[i] = 0.f;
#pragma unroll
    for (int kk = 0; kk < 16; kk++) {
      const float4 av = *(const float4*)(&As[kk][tm]);
      const float4 bv = *(const float4*)(&Bs[kk][tn]);
      float af[4] = {av.x, av.y, av.z, av.w};
      float bf[4] = {bv.x, bv.y, bv.z, bv.w};
#pragma unroll
      for (int i = 0; i < 4; i++)
#pragma unroll
        for (int j = 0; j < 4; j++) facc[i * 4 + j] += af[i] * bf[j];
    }
    __syncthreads();
#pragma unroll
    for (int i = 0; i < 16; i++) dacc[i] += (double)facc[i];
  }
#pragma unroll
  for (int i = 0; i < 4; i++) {
    int m = m0 + tm + i;
#pragma unroll
    for (int j = 0; j < 4; j++) {
      int n = n0 + tn + j;
      float v = (float)dacc[i * 4 + j] * scale;
      if (bias) v += bias[n];
      if (act) v = fmaxf(v, 0.f);
      C[(size_t)m * N + n] = v;
    }
  }
}

// ---------------- bf16x3 MFMA GEMM (NT): C = act(A@B^T + bias) ----------------
// A fp32 M x K, B fp32 N x K, C fp32 M x N.  Requires M%256==0, N%256==0, K%32==0.
// fp32 operands split on the fly: x = hi(bf16 RNE) + lo(bf16 of exact residual);
// 3 MFMA passes per fragment pair (hh, hl, lh) accumulate in fp32.
// 256x256 tile, BK=32, 8 waves (wave tile 64m x 128n), double-buffered LDS (128KB).

typedef __attribute__((ext_vector_type(8))) short bfrag;   // 8 bf16 (4 VGPRs)
typedef __attribute__((ext_vector_type(4))) float fragC;   // 4 fp32 acc

#define XBM 256
#define XBN 256
#define XBK 32

__device__ __forceinline__ void split1(float x, unsigned short& h, unsigned short& l) {
  unsigned u = __float_as_uint(x);
  unsigned hu = (u + (0x7fffu + ((u >> 16) & 1u))) & 0xffff0000u;  // RNE hi
  h = (unsigned short)(hu >> 16);
  l = (unsigned short)(__float_as_uint(x - __uint_as_float(hu)) >> 16);  // trunc lo
}

__global__ __launch_bounds__(512, 2) void gemm_nt_bf16x3(
    const float* __restrict__ A, const float* __restrict__ Bw,
    const float* __restrict__ bias, float* __restrict__ C,
    int M, int N, int K, int act) {
  __shared__ unsigned short Ah[2][XBM * XBK];
  __shared__ unsigned short Al[2][XBM * XBK];
  __shared__ unsigned short Bh[2][XBN * XBK];
  __shared__ unsigned short Bl[2][XBN * XBK];

  // XCD-aware swizzle (bijective: nwg % 8 == 0 for our shapes)
  int wg = blockIdx.y * gridDim.x + blockIdx.x;
  const int nwg = gridDim.x * gridDim.y;
  if ((nwg & 7) == 0) wg = (wg & 7) * (nwg >> 3) + (wg >> 3);
  const int bx = wg % gridDim.x, by = wg / gridDim.x;
  const int m0 = by * XBM, n0 = bx * XBN;

  const int tid = threadIdx.x;
  const int lane = tid & 63, wid = tid >> 6;
  const int wm = wid >> 1, wn = wid & 1;     // 4x2 wave grid, wave tile 64 x 128
  const int lrow = lane & 15, lkb = lane >> 4;

  // staging: thread loads 4 A-float4 + 4 B-float4 per K-step
  const int trow = tid >> 3, tc4 = tid & 7;  // row-in-tile (0..63, +i*64), k-quad
  const float* Ap = A + (size_t)(m0 + trow) * K + tc4 * 4;
  const float* Bp = Bw + (size_t)(n0 + trow) * K + tc4 * 4;
  const int wbase = trow * XBK + ((tc4 * 4) ^ (((trow >> 1) & 3) << 3));

  // fragment read offsets (contiguous-8 k per lane; row-XOR swizzle)
  const int rsw = (lkb * 8) ^ (((lrow >> 1) & 3) << 3);
  const int aoff = (wm * 64 + lrow) * XBK + rsw;
  const int boff = (wn * 128 + lrow) * XBK + rsw;

  fragC acc[4][8];
#pragma unroll
  for (int m = 0; m < 4; m++)
#pragma unroll
    for (int n = 0; n < 8; n++) {
      fragC z = {0.f, 0.f, 0.f, 0.f};
      acc[m][n] = z;
    }

  float4 ra[4], rb[4];

#define LOADT(kk)                                                     \
  {                                                                   \
    _Pragma("unroll")                                                 \
    for (int i = 0; i < 4; i++) {                                     \
      ra[i] = *(const float4*)(Ap + (size_t)i * 64 * K + (kk));       \
      rb[i] = *(const float4*)(Bp + (size_t)i * 64 * K + (kk));       \
    }                                                                 \
  }

#define WRITET(buf)                                                   \
  {                                                                   \
    _Pragma("unroll")                                                 \
    for (int i = 0; i < 4; i++) {                                     \
      ushort4 h, l;                                                   \
      split1(ra[i].x, h.x, l.x); split1(ra[i].y, h.y, l.y);           \
      split1(ra[i].z, h.z, l.z); split1(ra[i].w, h.w, l.w);           \
      *(ushort4*)&Ah[buf][wbase + i * 2048] = h;                      \
      *(ushort4*)&Al[buf][wbase + i * 2048] = l;                      \
      split1(rb[i].x, h.x, l.x); split1(rb[i].y, h.y, l.y);           \
      split1(rb[i].z, h.z, l.z); split1(rb[i].w, h.w, l.w);           \
      *(ushort4*)&Bh[buf][wbase + i * 2048] = h;                      \
      *(ushort4*)&Bl[buf][wbase + i * 2048] = l;                      \
    }                                                                 \
  }

  LOADT(0);
  WRITET(0);
  const int NT = K / XBK;
  int cur = 0;
  for (int t = 0; t < NT; t++) {
    if (t + 1 < NT) LOADT((t + 1) * XBK);   // prefetch issues before barrier
    __syncthreads();                         // buf[cur] ready for all waves
    const unsigned short* pAh = Ah[cur]; const unsigned short* pAl = Al[cur];
    const unsigned short* pBh = Bh[cur]; const unsigned short* pBl = Bl[cur];
    bfrag fah[4], fal[4];
#pragma unroll
    for (int m = 0; m < 4; m++) {
      fah[m] = *(const bfrag*)&pAh[aoff + m * 16 * XBK];
      fal[m] = *(const bfrag*)&pAl[aoff + m * 16 * XBK];
    }
#pragma unroll
    for (int n = 0; n < 8; n++) {
      bfrag fbh = *(const bfrag*)&pBh[boff + n * 16 * XBK];
      bfrag fbl = *(const bfrag*)&pBl[boff + n * 16 * XBK];
#pragma unroll
      for (int m = 0; m < 4; m++) {
        acc[m][n] = __builtin_amdgcn_mfma_f32_16x16x32_bf16(fah[m], fbh, acc[m][n], 0, 0, 0);
        acc[m][n] = __builtin_amdgcn_mfma_f32_16x16x32_bf16(fah[m], fbl, acc[m][n], 0, 0, 0);
        acc[m][n] = __builtin_amdgcn_mfma_f32_16x16x32_bf16(fal[m], fbh, acc[m][n], 0, 0, 0);
      }
    }
    if (t + 1 < NT) WRITET(cur ^ 1);         // write next tile (other buffer)
    cur ^= 1;
  }
#undef LOADT
#undef WRITET

  // epilogue: C/D layout col = lane&15, row = (lane>>4)*4 + reg  (m89-verified)
#pragma unroll
  for (int m = 0; m < 4; m++) {
    const int row0 = m0 + wm * 64 + m * 16 + lkb * 4;
#pragma unroll
    for (int n = 0; n < 8; n++) {
      const int col = n0 + wn * 128 + n * 16 + lrow;
      const float badd = bias ? bias[col] : 0.f;
#pragma unroll
      for (int j = 0; j < 4; j++) {
        float v = acc[m][n][j] + badd;
        if (act) v = fmaxf(v, 0.f);
        C[(size_t)(row0 + j) * N + col] = v;
      }
    }
  }
}

// C[m,n] = sum_k Aeff[m,k]*B[k,n] (+bias). Aeff = A1 (+ proj[m]*A2).
// B fp32 row-major (ldb=N). Out fp32.
__global__ __launch_bounds__(256) void gemm_nn(const float* __restrict__ A1,
                                               const float* __restrict__ A2,
                                               const float* __restrict__ projv,
                                               const float* __restrict__ Bw,
                                               const float* __restrict__ bias,
                                               float* __restrict__ Cf,
                                               int M, int N, int K) {
  __shared__ float As[16][64];
  __shared__ float Bs[16][64];
  const int tid = threadIdx.x;
  const int m0 = blockIdx.y * 64;
  const int n0 = blockIdx.x * 64;
  const int lr = tid >> 2;          // A loader: 0..63 rows(m)
  const int lc = (tid & 3) << 2;    // k quad
  const int br = tid >> 4;          // B loader: 0..15 rows(k)
  const int bc = (tid & 15) << 2;   // n quad
  const int tm = (tid >> 4) << 2;
  const int tn = (tid & 15) << 2;
  double dacc[16];
#pragma unroll
  for (int i = 0; i < 16; i++) dacc[i] = 0.0;

  for (int k0 = 0; k0 < K; k0 += 16) {
    float4 a4 = *(const float4*)(A1 + (size_t)(m0 + lr) * K + k0 + lc);
    if (A2) {
      float p = projv[m0 + lr];
      float4 c4 = *(const float4*)(A2 + (size_t)(m0 + lr) * K + k0 + lc);
      a4.x += p * c4.x; a4.y += p * c4.y; a4.z += p * c4.z; a4.w += p * c4.w;
    }
    As[lc + 0][lr] = a4.x; As[lc + 1][lr] = a4.y;
    As[lc + 2][lr] = a4.z; As[lc + 3][lr] = a4.w;
    float4 b4 = *(const float4*)(Bw + (size_t)(k0 + br) * N + n0 + bc);
    Bs[br][bc + 0] = b4.x; Bs[br][bc + 1] = b4.y;
    Bs[br][bc + 2] = b4.z; Bs[br][bc + 3] = b4.w;
    __syncthreads();
    float facc[16];
#pragma unroll
    for (int i = 0; i < 16; i++) facc[i] = 0.f;
#pragma unroll
    for (int kk = 0; kk < 16; kk++) {
      const float4 av = *(const float4*)(&As[kk][tm]);
      const float4 bv = *(const float4*)(&Bs[kk][tn]);
      float af[4] = {av.x, av.y, av.z, av.w};
      float bf[4] = {bv.x, bv.y, bv.z, bv.w};
#pragma unroll
      for (int i = 0; i < 4; i++)
#pragma unroll
        for (int j = 0; j < 4; j++) facc[i * 4 + j] += af[i] * bf[j];
    }
    __syncthreads();
#pragma unroll
    for (int i = 0; i < 16; i++) dacc[i] += (double)facc[i];
  }
#pragma unroll
  for (int i = 0; i < 4; i++) {
    int m = m0 + tm + i;
#pragma unroll
    for (int j = 0; j < 4; j++) {
      int n = n0 + tn + j;
      float v = (float)dacc[i * 4 + j];
      if (bias) v += bias[n];
      Cf[(size_t)m * N + n] = v;
    }
  }
}

// a[bh,t,s] = causal softmax( q(t)·k(s)/4 );  k(0)=bk, k(s)=kz[b,s-1]
__global__ __launch_bounds__(256) void attn_softmax(const float* __restrict__ qz,
                                                    const float* __restrict__ kz,
                                                    const float* __restrict__ bk,
                                                    float* __restrict__ aout) {
  const int blk = blockIdx.x;
  const int t  = blk & (TT - 1);
  const int bh = blk >> 9;
  const int h  = bh & (NH - 1);
  const int bb = bh >> 3;
  __shared__ float qs[DHQK];
  __shared__ float red[256];
  const int tid = threadIdx.x;
  if (tid < DHQK) qs[tid] = qz[(size_t)(bb * TT + t) * NE + h * DHQK + tid];
  __syncthreads();
  float sc[2];
#pragma unroll
  for (int j = 0; j < 2; j++) {
    int s = tid + j * 256;
    float v = -__builtin_inff();
    if (s <= t) {
      float d = 0.f;
      if (s == 0) {
#pragma unroll
        for (int i = 0; i < DHQK; i++) d += qs[i] * bk[h * DHQK + i];
      } else {
        const float* kp = kz + (size_t)(bb * TT + s - 1) * NE + h * DHQK;
#pragma unroll
        for (int i = 0; i < DHQK; i++) d += qs[i] * kp[i];
      }
      v = d * 0.25f;
    }
    sc[j] = v;
  }
  red[tid] = fmaxf(sc[0], sc[1]);
  __syncthreads();
  for (int s2 = 128; s2 > 0; s2 >>= 1) {
    if (tid < s2) red[tid] = fmaxf(red[tid], red[tid + s2]);
    __syncthreads();
  }
  const float mx = red[0];
  __syncthreads();
  float e0 = expf(sc[0] - mx), e1 = expf(sc[1] - mx);
  red[tid] = e0 + e1;
  __syncthreads();
  for (int s2 = 128; s2 > 0; s2 >>= 1) {
    if (tid < s2) red[tid] += red[tid + s2];
    __syncthreads();
  }
  const float inv = 1.f / red[0];
  const size_t base = ((size_t)bh * TT + t) * TT;
  aout[base + tid]       = e0 * inv;
  aout[base + tid + 256] = e1 * inv;
}

// o[b, t, h*DHV + d] = sum_s a[bh,t,s] * v(s)[h,d]; v(0)=bv, v(s)=vz[b,s-1]
__global__ __launch_bounds__(256) void attn_o(const float* __restrict__ a,
                                              const float* __restrict__ vz,
                                              const float* __restrict__ bv,
                                              float* __restrict__ o) {
  const int bh = blockIdx.y, bb = bh >> 3, h = bh & 7;
  const int tile = blockIdx.x;         // 8 m-tiles x 16 n-tiles
  const int m0 = (tile & 7) * 64;
  const int n0 = (tile >> 3) * 64;
  const float* A = a + (size_t)bh * TT * TT;
  __shared__ float As[16][64];
  __shared__ float Bs[16][64];
  const int tid = threadIdx.x;
  const int lr = tid >> 2, lc = (tid & 3) << 2;
  const int br = tid >> 4, bc = (tid & 15) << 2;
  const int tm = (tid >> 4) << 2, tn = (tid & 15) << 2;
  double dacc[16];
#pragma unroll
  for (int i = 0; i < 16; i++) dacc[i] = 0.0;

  for (int k0 = 0; k0 < TT; k0 += 16) {
    float4 a4 = *(const float4*)(A + (size_t)(m0 + lr) * TT + k0 + lc);
    As[lc + 0][lr] = a4.x; As[lc + 1][lr] = a4.y;
    As[lc + 2][lr] = a4.z; As[lc + 3][lr] = a4.w;
    const int s = k0 + br;
    float4 b4;
    if (s == 0) {
      b4.x = bv[h * DHV + n0 + bc + 0];
      b4.y = bv[h * DHV + n0 + bc + 1];
      b4.z = bv[h * DHV + n0 + bc + 2];
      b4.w = bv[h * DHV + n0 + bc + 3];
    } else {
      b4 = *(const float4*)(vz + (size_t)(bb * TT + s - 1) * WIDTH + h * DHV + n0 + bc);
    }
    Bs[br][bc + 0] = b4.x; Bs[br][bc + 1] = b4.y;
    Bs[br][bc + 2] = b4.z; Bs[br][bc + 3] = b4.w;
    __syncthreads();
    float facc[16];
#pragma unroll
    for (int i = 0; i < 16; i++) facc[i] = 0.f;
#pragma unroll
    for (int kk = 0; kk < 16; kk++) {
      const float4 av = *(const float4*)(&As[kk][tm]);
      const float4 bv4 = *(const float4*)(&Bs[kk][tn]);
      float af[4] = {av.x, av.y, av.z, av.w};
      float bf[4] = {bv4.x, bv4.y, bv4.z, bv4.w};
#pragma unroll
      for (int i = 0; i < 4; i++)
#pragma unroll
        for (int j = 0; j < 4; j++) facc[i * 4 + j] += af[i] * bf[j];
    }
    __syncthreads();
#pragma unroll
    for (int i = 0; i < 16; i++) dacc[i] += (double)facc[i];
  }
#pragma unroll
  for (int i = 0; i < 4; i++)
#pragma unroll
    for (int j = 0; j < 4; j++)
      o[(size_t)(bb * TT + m0 + tm + i) * WIDTH + h * DHV + n0 + tn + j] =
          (float)dacc[i * 4 + j];
}

// proj[r] = <Dz,x0>/(<Dz,Dz>+1e-6);  x0 -= proj*Dz  (in place)
__global__ __launch_bounds__(256) void proj_update(const float* __restrict__ Dz,
                                                   float* __restrict__ x0,
                                                   float* __restrict__ projv) {
  const int r = blockIdx.x;
  __shared__ double r1[256], r2[256];
  __shared__ float pp;
  const int tid = threadIdx.x;
  double s1 = 0.0, s2 = 0.0;
  for (int i = tid; i < DIMIN; i += 256) {
    float dz = Dz[(size_t)r * DIMIN + i];
    float xx = x0[(size_t)r * DIMIN + i];
    s1 += (double)dz * (double)xx;
    s2 += (double)dz * (double)dz;
  }
  r1[tid] = s1; r2[tid] = s2;
  __syncthreads();
  for (int s = 128; s > 0; s >>= 1) {
    if (tid < s) { r1[tid] += r1[tid + s]; r2[tid] += r2[tid + s]; }
    __syncthreads();
  }
  if (tid == 0) {
    float p = (float)(r1[0] / (r2[0] + 1e-6));
    pp = p; projv[r] = p;
  }
  __syncthreads();
  const float p = pp;
  for (int i = tid; i < DIMIN; i += 256)
    x0[(size_t)r * DIMIN + i] -= p * Dz[(size_t)r * DIMIN + i];
}

// in-place top-k mask of one row of z (values >= 0 post-relu).
// Iterative argmax, tie -> lowest index (matches lax.top_k).
__global__ __launch_bounds__(256) void topk_mask(float* __restrict__ z,
                                                 const int* __restrict__ kvp) {
  const int r = blockIdx.x;
  __shared__ float buf[WIDTH];
  __shared__ float rv[256];
  __shared__ int ri[256];
  const int tid = threadIdx.x;
  float* zr = z + (size_t)r * WIDTH;
  for (int i = tid; i < WIDTH; i += 256) buf[i] = zr[i];
  const int kv = kvp[0];
  __syncthreads();
  for (int it = 0; it < kv; it++) {
    float best = -1.0f; int bi = 1 << 30;
    const int base = tid * 32;
#pragma unroll
    for (int jj = 0; jj < 32; jj++) {
      int i = base + ((jj + tid) & 31);   // bank-conflict-free rotation
      float v = buf[i];
      if (v > best || (v == best && i < bi)) { best = v; bi = i; }
    }
    rv[tid] = best; ri[tid] = bi;
    __syncthreads();
    for (int s = 128; s > 0; s >>= 1) {
      if (tid < s) {
        float v2 = rv[tid + s]; int i2 = ri[tid + s];
        if (v2 > rv[tid] || (v2 == rv[tid] && i2 < ri[tid])) { rv[tid] = v2; ri[tid] = i2; }
      }
      __syncthreads();
    }
    if (tid == 0) buf[ri[0]] = -2.0f;   // mark selected
    __syncthreads();
  }
  for (int i = tid; i < WIDTH; i += 256)
    zr[i] = (buf[i] == -2.0f) ? zr[i] : 0.0f;
}

extern "C" void kernel_launch(void* const* d_in, const int* in_sizes, int n_in,
                              void* d_out, int out_size, void* d_ws, size_t ws_size,
                              hipStream_t stream) {
  const float* x_in = (const float*)d_in[0];
  const float* D    = (const float*)d_in[1];
  const float* bb_  = (const float*)d_in[2];
  const float* Wk   = (const float*)d_in[3];
  const float* bk   = (const float*)d_in[4];
  const float* Wq   = (const float*)d_in[5];
  const float* bq   = (const float*)d_in[6];
  const float* Wv   = (const float*)d_in[7];
  const float* bv   = (const float*)d_in[8];
  const float* Wo   = (const float*)d_in[9];
  const float* bo   = (const float*)d_in[10];
  const int* kval   = (const int*)d_in[11];

  char* ws = (char*)d_ws;
  float* big0 = (float*)(ws + 0LL);           // z_in -> o -> z_novel   (128 MB)
  float* big1 = (float*)(ws + 134217728LL);   // vz   -> z_pred_        (128 MB)
  float* amat = (float*)(ws + 268435456LL);   // attention weights      (64 MB)
  float* x0   = (float*)(ws + 335544320LL);   // x residual             (12 MB)
  float* Dzb  = (float*)(ws + 348127232LL);   // Dz                     (12 MB)
  float* kz   = (float*)(ws + 360710144LL);
  float* qz   = (float*)(ws + 362807296LL);
  float* pr   = (float*)(ws + 364904448LL);

  const float lam = 1.0f / 3072.0f;

  // x = x_input - b
  sub_bias<<<(MROWS * DIMIN) / 256, 256, 0, stream>>>(x_in, bb_, x0, MROWS * DIMIN);
  // z_in = relu(lam * x @ D^T)
  gemm_nt<<<dim3(WIDTH / 64, MROWS / 64), 256, 0, stream>>>(
      x0, D, nullptr, big0, MROWS, WIDTH, DIMIN, lam, 1);
  // q,k,v projections (unshifted; shift handled inside attention)
  gemm_nt<<<dim3(NE / 64, MROWS / 64), 256, 0, stream>>>(
      big0, Wq, bq, qz, MROWS, NE, WIDTH, 1.f, 0);
  gemm_nt<<<dim3(NE / 64, MROWS / 64), 256, 0, stream>>>(
      big0, Wk, bk, kz, MROWS, NE, WIDTH, 1.f, 0);
  // v = z_in @ Wv^T + bv   (bf16x3 MFMA)
  gemm_nt_bf16x3<<<dim3(WIDTH / XBN, MROWS / XBM), 512, 0, stream>>>(
      big0, Wv, bv, big1, MROWS, WIDTH, WIDTH, 0);
  // attention
  attn_softmax<<<BB * NH * TT, 256, 0, stream>>>(qz, kz, bk, amat);
  attn_o<<<dim3(128, BB * NH), 256, 0, stream>>>(amat, big1, bv, big0);
  // z_pred_ = relu(o @ Wo^T + bo)   (bf16x3 MFMA)
  gemm_nt_bf16x3<<<dim3(WIDTH / XBN, MROWS / XBM), 512, 0, stream>>>(
      big0, Wo, bo, big1, MROWS, WIDTH, WIDTH, 1);
  // Dz = z_pred_ @ D
  gemm_nn<<<dim3(DIMIN / 64, MROWS / 64), 256, 0, stream>>>(
      big1, nullptr, nullptr, D, nullptr, Dzb, MROWS, DIMIN, WIDTH);
  // proj + residual update (x0 := x - proj*Dz)
  proj_update<<<MROWS, 256, 0, stream>>>(Dzb, x0, pr);
  // z_novel = relu(lam * x_new @ D^T)
  gemm_nt<<<dim3(WIDTH / 64, MROWS / 64), 256, 0, stream>>>(
      x0, D, nullptr, big0, MROWS, WIDTH, DIMIN, lam, 1);
  // top-k sparsify in place
  topk_mask<<<MROWS, 256, 0, stream>>>(big0, kval);
  // x_recons = (z_novel + proj*z_pred_) @ D + b   (fp32 out)
  gemm_nn<<<dim3(DIMIN / 64, MROWS / 64), 256, 0, stream>>>(
      big0, big1, pr, D, bb_, (float*)d_out, MROWS, DIMIN, WIDTH);
}